// Round 1
// baseline (731.549 us; speedup 1.0000x reference)
//
#include <hip/hip_runtime.h>
#include <math.h>

#define NF 12
#define NC 27
#define KD 5
#define T_IN 65536
#define T_OUT 65532
#define TILE 1024   // 256 threads * 4 floats

__global__ __launch_bounds__(256) void sinc_conv_kernel(
    const float* __restrict__ x,
    const float* __restrict__ flow,
    const float* __restrict__ fband,
    float* __restrict__ out)
{
    __shared__ float sf[NF][KD];

    const int tid = threadIdx.x;
    const int c  = blockIdx.y;
    const int b  = blockIdx.z;

    // ---- build this channel's 12 filters (threads 0..11) ----
    if (tid < NF) {
        const float PI = 3.14159265358979323846f;
        float lo = fabsf(flow[c * NF + tid]) + 0.01f;   // MIN_FREQ/FS
        float hi = lo + fabsf(fband[c * NF + tid]);

        float bp[KD];
        bp[2] = 2.0f * hi - 2.0f * lo;                  // center tap (sinc(0)=1)
        #pragma unroll
        for (int j = 1; j <= 2; ++j) {
            // arg = 2*pi*FS*freq*(j/FS) = 2*pi*freq*j
            float ah = 2.0f * PI * hi * (float)j;
            float al = 2.0f * PI * lo * (float)j;
            float v = 2.0f * hi * (sinf(ah) / ah) - 2.0f * lo * (sinf(al) / al);
            bp[2 + j] = v;
            bp[2 - j] = v;
        }
        float mx = bp[0];
        #pragma unroll
        for (int k = 1; k < KD; ++k) mx = fmaxf(mx, bp[k]);

        #pragma unroll
        for (int k = 0; k < KD; ++k) {
            // window: n = linspace(0, 5, 5) -> step 1.25
            float n = 1.25f * (float)k;
            float win = 0.42f - 0.5f * cosf(2.0f * PI * n / 5.0f)
                              + 0.08f * cosf(4.0f * PI * n / 5.0f);
            sf[tid][k] = (bp[k] / mx) * win;
        }
    }
    __syncthreads();

    // ---- conv: each thread does 4 consecutive t for all 12 filters ----
    const int t0 = blockIdx.x * TILE + tid * 4;
    if (t0 >= T_OUT) return;   // only thread with t0==65532 in the last tile

    const float* xrow = x + (size_t)(b * NC + c) * T_IN;
    const float4* x4 = (const float4*)xrow;
    float4 A = x4[t0 >> 2];
    float4 B = x4[(t0 >> 2) + 1];
    float xv0 = A.x, xv1 = A.y, xv2 = A.z, xv3 = A.w;
    float xv4 = B.x, xv5 = B.y, xv6 = B.z, xv7 = B.w;

    float* obase = out + (size_t)(b * NC + c) * NF * T_OUT;

    #pragma unroll
    for (int f = 0; f < NF; ++f) {
        float w0 = sf[f][0], w1 = sf[f][1], w2 = sf[f][2], w3 = sf[f][3], w4 = sf[f][4];
        float4 o;
        o.x = xv0 * w0 + xv1 * w1 + xv2 * w2 + xv3 * w3 + xv4 * w4;
        o.y = xv1 * w0 + xv2 * w1 + xv3 * w2 + xv4 * w3 + xv5 * w4;
        o.z = xv2 * w0 + xv3 * w1 + xv4 * w2 + xv5 * w3 + xv6 * w4;
        o.w = xv3 * w0 + xv4 * w1 + xv5 * w2 + xv6 * w3 + xv7 * w4;
        float4* orow = (float4*)(obase + (size_t)f * T_OUT);
        orow[t0 >> 2] = o;
    }
}

extern "C" void kernel_launch(void* const* d_in, const int* in_sizes, int n_in,
                              void* d_out, int out_size, void* d_ws, size_t ws_size,
                              hipStream_t stream) {
    const float* x     = (const float*)d_in[0];
    const float* flow  = (const float*)d_in[1];
    const float* fband = (const float*)d_in[2];
    float* out = (float*)d_out;

    dim3 grid((T_IN + TILE - 1) / TILE, NC, 8);   // 64 x 27 x 8
    dim3 block(256);
    sinc_conv_kernel<<<grid, block, 0, stream>>>(x, flow, fband, out);
}